// Round 1
// 571.234 us; speedup vs baseline: 1.1013x; 1.1013x over previous
//
#include <hip/hip_runtime.h>

#define SEQ   16384
#define DIM   2048
#define CHUNK 128
#define NCHUNK (SEQ / CHUNK)   // 128

typedef __attribute__((ext_vector_type(8))) short  short8;
typedef __attribute__((ext_vector_type(4))) short  short4v;
typedef __attribute__((ext_vector_type(4))) float  floatx4;

static __device__ __forceinline__ float bf2f(short s) {
    return __uint_as_float(((unsigned)(unsigned short)s) << 16);
}
static __device__ __forceinline__ short f2bf(float f) {
    unsigned u = __float_as_uint(f);
    u += 0x7fff + ((u >> 16) & 1);   // RNE
    return (short)(u >> 16);
}

// ---------- fp32 -> bf16 cast, float4 vectorized ----------
__global__ void cast_kernel(const float* __restrict__ in, short* __restrict__ out, int n4) {
    int i = blockIdx.x * blockDim.x + threadIdx.x;
    if (i >= n4) return;
    float4 v = ((const float4*)in)[i];
    short4v s;
    s.x = f2bf(v.x); s.y = f2bf(v.y); s.z = f2bf(v.z); s.w = f2bf(v.w);
    ((short4v*)out)[i] = s;
}

// ---------- bf16 GEMM, C[m][n] = sum_k A[m][k]*B[n][k] (both K-contiguous) ----------
// 256x256 tile, BK=64, 512 threads = 8 waves (2M x 4N), wave => 128x64 output.
// 8-phase schedule, double-buffered 128 KiB LDS, counted vmcnt(6), XOR-8 slot swizzle.
// FUSE==0: store bf16 C. FUSE==1: store fp32 C + xs*dskip.

#define BAR   __builtin_amdgcn_s_barrier()
#define PRIO1 __builtin_amdgcn_s_setprio(1)
#define PRIO0 __builtin_amdgcn_s_setprio(0)
#define LGKM0 do { asm volatile("s_waitcnt lgkmcnt(0)" ::: "memory"); \
                   __builtin_amdgcn_sched_barrier(0); } while (0)
#define VMC6  asm volatile("s_waitcnt vmcnt(6)" ::: "memory")
#define VMC0  asm volatile("s_waitcnt vmcnt(0)" ::: "memory")

// stage one 128x64 half-tile (16 KiB): 2 x global_load_lds(16B) per thread.
// LDS dest is linear (chunk c at shorts c*8); global source slot is XOR-swizzled
// so that a swizzled ds_read sees logical data (involution: s_src = s ^ (row&7)).
#define STAGE_A(b, h, t) do { \
    const short* _s = Abase + (size_t)(h) * 128 * K + (size_t)(t) * 64; \
    __builtin_amdgcn_global_load_lds(_s + gOff0, &As[b][h][c0 * 8], 16, 0, 0); \
    __builtin_amdgcn_global_load_lds(_s + gOff1, &As[b][h][c1 * 8], 16, 0, 0); \
} while (0)
#define STAGE_B(b, h, t) do { \
    const short* _s = Bbase + (size_t)(h) * 128 * K + (size_t)(t) * 64; \
    __builtin_amdgcn_global_load_lds(_s + gOff0, &Bs[b][h][c0 * 8], 16, 0, 0); \
    __builtin_amdgcn_global_load_lds(_s + gOff1, &Bs[b][h][c1 * 8], 16, 0, 0); \
} while (0)

// fragment reads: logical slot (ks*4+quad), physical slot XOR (row&7) = (l16&7)
#define LDA(b, mh) \
    _Pragma("unroll") \
    for (int mi = 0; mi < 4; mi++) { \
        _Pragma("unroll") \
        for (int ks = 0; ks < 2; ks++) \
            aV[mi][ks] = *(const short8*)&As[b][mh][(arow + mi * 16) * 64 + \
                                                    ((((ks << 2) | quad) ^ sx) << 3)]; \
    }
#define LDB(dst, b, nh) \
    _Pragma("unroll") \
    for (int ni = 0; ni < 2; ni++) { \
        _Pragma("unroll") \
        for (int ks = 0; ks < 2; ks++) \
            dst[ni][ks] = *(const short8*)&Bs[b][nh][(brow + ni * 16) * 64 + \
                                                     ((((ks << 2) | quad) ^ sx) << 3)]; \
    }
#define MMA(mh, nh, bR) \
    _Pragma("unroll") \
    for (int mi = 0; mi < 4; mi++) { \
        _Pragma("unroll") \
        for (int ni = 0; ni < 2; ni++) { \
            acc[mh][nh][mi][ni] = __builtin_amdgcn_mfma_f32_16x16x32_bf16( \
                aV[mi][0], bR[ni][0], acc[mh][nh][mi][ni], 0, 0, 0); \
            acc[mh][nh][mi][ni] = __builtin_amdgcn_mfma_f32_16x16x32_bf16( \
                aV[mi][1], bR[ni][1], acc[mh][nh][mi][ni], 0, 0, 0); \
        } \
    }

template<int FUSE>
__global__ __launch_bounds__(512, 2)
void gemm_bt(const short* __restrict__ A, const short* __restrict__ B,
             short* __restrict__ Cbf, float* __restrict__ Cf,
             const float* __restrict__ xs, const float* __restrict__ dskip)
{
    constexpr int K  = DIM;        // 2048
    constexpr int NT = K / 64;     // 32 K-tiles

    __shared__ alignas(16) short As[2][2][128 * 64];   // [buf][half][row*64+slot*8]
    __shared__ alignas(16) short Bs[2][2][128 * 64];

    const int tid = threadIdx.x;
    const int m0  = blockIdx.y * 256;
    const int n0  = blockIdx.x * 256;   // gridDim.x==8 == NXCD: one B-panel per XCD

    const int lane = tid & 63;
    const int wv   = tid >> 6;
    const int wrow = wv >> 2;           // 0..1
    const int wcol = wv & 3;            // 0..3
    const int l16  = lane & 15;
    const int quad = lane >> 4;
    const int sx   = l16 & 7;
    const int arow = wrow * 64 + l16;   // local row in A half-region (strided map)
    const int brow = wcol * 32 + l16;   // local row in B half-region

    // staging constants: chunks c0, c1 of each half-tile (1024 x 16B chunks)
    const int c0 = tid, c1 = tid + 512;
    const int r0 = c0 >> 3, r1 = c1 >> 3;
    const size_t gOff0 = (size_t)r0 * K + (size_t)((((c0 & 7) ^ (r0 & 7))) * 8);
    const size_t gOff1 = (size_t)r1 * K + (size_t)((((c1 & 7) ^ (r1 & 7))) * 8);
    const short* Abase = A + (size_t)m0 * K;
    const short* Bbase = B + (size_t)n0 * K;

    short8  aV[4][2], bA[2][2], bB[2][2];
    floatx4 acc[2][2][4][2] = {};   // [mh][nh][mi][ni]

    // ---- prologue: tile0 -> buf0 (8 loads), tile1 {Ah0,Bh0,Bh1} -> buf1 (6 loads)
    STAGE_A(0, 0, 0); STAGE_B(0, 0, 0); STAGE_B(0, 1, 0); STAGE_A(0, 1, 0);
    STAGE_A(1, 0, 1); STAGE_B(1, 0, 1); STAGE_B(1, 1, 1);
    VMC6;           // oldest 8 (= all of tile0) landed
    BAR;

    for (int i = 0; i < NT / 2; ++i) {
        const int t1 = 2 * i + 1;
        const int t2 = (2 * i + 2) & (NT - 1);   // wrap: tail stages harmless
        const int t3 = (2 * i + 3) & (NT - 1);

        // P1: read buf0.Ah0 + buf0.Bh0 ; stage buf1.Ah1 <- t1
        LDA(0, 0); LDB(bA, 0, 0); STAGE_A(1, 1, t1);
        BAR; LGKM0;
        PRIO1; MMA(0, 0, bA); PRIO0;
        BAR;
        // P2: read buf0.Bh1 ; stage buf0.Ah0 <- t2
        LDB(bB, 0, 1); STAGE_A(0, 0, t2);
        BAR; LGKM0;
        PRIO1; MMA(0, 1, bB); PRIO0;
        BAR;
        // P3: read buf0.Ah1 ; stage buf0.Bh0 <- t2
        LDA(0, 1); STAGE_B(0, 0, t2);
        BAR; LGKM0;
        PRIO1; MMA(1, 0, bA); PRIO0;
        BAR;
        // P4: stage buf0.Bh1 <- t2 ; counted drain: buf1 fully ready
        STAGE_B(0, 1, t2);
        BAR;
        PRIO1; MMA(1, 1, bB); PRIO0;
        VMC6;
        BAR;
        // P5: read buf1.Ah0 + buf1.Bh0 ; stage buf0.Ah1 <- t2
        LDA(1, 0); LDB(bA, 1, 0); STAGE_A(0, 1, t2);
        BAR; LGKM0;
        PRIO1; MMA(0, 0, bA); PRIO0;
        BAR;
        // P6: read buf1.Bh1 ; stage buf1.Ah0 <- t3
        LDB(bB, 1, 1); STAGE_A(1, 0, t3);
        BAR; LGKM0;
        PRIO1; MMA(0, 1, bB); PRIO0;
        BAR;
        // P7: read buf1.Ah1 ; stage buf1.Bh0 <- t3
        LDA(1, 1); STAGE_B(1, 0, t3);
        BAR; LGKM0;
        PRIO1; MMA(1, 0, bA); PRIO0;
        BAR;
        // P8: stage buf1.Bh1 <- t3 ; counted drain: buf0 fully ready
        STAGE_B(1, 1, t3);
        BAR;
        PRIO1; MMA(1, 1, bB); PRIO0;
        VMC6;
        BAR;
    }
    VMC0;   // no LDS-DMA may outlive this workgroup

    // ---- epilogue: C row = m0+wrow*64+mh*128+mi*16+quad*4+r, col = n0+wcol*32+nh*128+ni*16+l16
    if (FUSE == 0) {
        #pragma unroll
        for (int mh = 0; mh < 2; mh++)
        #pragma unroll
        for (int mi = 0; mi < 4; mi++) {
            const int rb = m0 + wrow * 64 + mh * 128 + mi * 16 + quad * 4;
            #pragma unroll
            for (int nh = 0; nh < 2; nh++)
            #pragma unroll
            for (int ni = 0; ni < 2; ni++) {
                const int cc = n0 + wcol * 32 + nh * 128 + ni * 16 + l16;
                #pragma unroll
                for (int r = 0; r < 4; r++)
                    Cbf[(size_t)(rb + r) * DIM + cc] = f2bf(acc[mh][nh][mi][ni][r]);
            }
        }
    } else {
        float dsk[2][2];
        #pragma unroll
        for (int nh = 0; nh < 2; nh++)
        #pragma unroll
        for (int ni = 0; ni < 2; ni++)
            dsk[nh][ni] = dskip[n0 + wcol * 32 + nh * 128 + ni * 16 + l16];
        #pragma unroll
        for (int mh = 0; mh < 2; mh++)
        #pragma unroll
        for (int mi = 0; mi < 4; mi++) {
            const int rb = m0 + wrow * 64 + mh * 128 + mi * 16 + quad * 4;
            #pragma unroll
            for (int nh = 0; nh < 2; nh++)
            #pragma unroll
            for (int ni = 0; ni < 2; ni++) {
                const int cc = n0 + wcol * 32 + nh * 128 + ni * 16 + l16;
                #pragma unroll
                for (int r = 0; r < 4; r++) {
                    size_t idx = (size_t)(rb + r) * DIM + cc;
                    Cf[idx] = acc[mh][nh][mi][ni][r] + xs[idx] * dsk[nh][ni];
                }
            }
        }
    }
}

// ---------- scan pass 1: per-chunk local final state (zero init), 2 cols/thread ----------
__global__ void scan_pass1(const short* __restrict__ bx, const float* __restrict__ lam,
                           float* __restrict__ blockLast)
{
    int n2    = blockIdx.x * 256 + threadIdx.x;   // column-pair id
    int n     = n2 * 2;
    int chunk = blockIdx.y;
    float lm0 = lam[n], lm1 = lam[n + 1];
    const unsigned* p = (const unsigned*)(bx + (size_t)chunk * CHUNK * DIM) + n2;
    float h0 = 0.f, h1 = 0.f;
    #pragma unroll 16
    for (int i = 0; i < CHUNK; i++) {
        unsigned v = p[(size_t)i * (DIM / 2)];
        h0 = fmaf(lm0, h0, bf2f((short)(v & 0xffffu)));
        h1 = fmaf(lm1, h1, bf2f((short)(v >> 16)));
    }
    float2 o; o.x = h0; o.y = h1;
    *(float2*)&blockLast[(size_t)chunk * DIM + n] = o;
}

// ---------- scan pass 2: exclusive prefix over chunks (in place) ----------
__global__ void scan_pass2(float* __restrict__ blockLast, const float* __restrict__ lam)
{
    int n2 = blockIdx.x * 256 + threadIdx.x;
    int n  = n2 * 2;
    float lm0 = lam[n], lm1 = lam[n + 1];
    float p0 = lm0, p1 = lm1;
    #pragma unroll
    for (int i = 0; i < 7; i++) { p0 *= p0; p1 *= p1; }   // lam^128
    float c0 = 0.f, c1 = 0.f;
    for (int c = 0; c < NCHUNK; c++) {
        float2* q = (float2*)&blockLast[(size_t)c * DIM + n];
        float2 t = *q;
        float2 w; w.x = c0; w.y = c1;
        *q = w;
        c0 = fmaf(p0, c0, t.x);
        c1 = fmaf(p1, c1, t.y);
    }
}

// ---------- scan pass 3: apply carry, write hs (bf16, in place over bx) ----------
__global__ void scan_pass3(short* __restrict__ bxh, const float* __restrict__ lam,
                           const float* __restrict__ carry)
{
    int n2    = blockIdx.x * 256 + threadIdx.x;
    int n     = n2 * 2;
    int chunk = blockIdx.y;
    float lm0 = lam[n], lm1 = lam[n + 1];
    float h0  = carry[(size_t)chunk * DIM + n];
    float h1  = carry[(size_t)chunk * DIM + n + 1];
    unsigned* p = (unsigned*)(bxh + (size_t)chunk * CHUNK * DIM) + n2;
    #pragma unroll 16
    for (int i = 0; i < CHUNK; i++) {
        unsigned v = p[(size_t)i * (DIM / 2)];
        h0 = fmaf(lm0, h0, bf2f((short)(v & 0xffffu)));
        h1 = fmaf(lm1, h1, bf2f((short)(v >> 16)));
        p[(size_t)i * (DIM / 2)] = (unsigned)(unsigned short)f2bf(h0)
                                 | ((unsigned)(unsigned short)f2bf(h1) << 16);
    }
}

extern "C" void kernel_launch(void* const* d_in, const int* in_sizes, int n_in,
                              void* d_out, int out_size, void* d_ws, size_t ws_size,
                              hipStream_t stream)
{
    const float* xs    = (const float*)d_in[0];
    const float* lam   = (const float*)d_in[1];
    const float* w_in  = (const float*)d_in[2];
    const float* c_out = (const float*)d_in[3];
    const float* dskip = (const float*)d_in[4];
    float* out = (float*)d_out;

    // ws layout:
    //   [0,   64M) : bx / hs  bf16  [SEQ][DIM]
    //   [64M, 72M) : w_in     bf16  [DIM][DIM]
    //   [72M, 80M) : c_out    bf16  [DIM][DIM]
    char*  ws    = (char*)d_ws;
    short* bxh   = (short*)ws;
    short* w_bf  = (short*)(ws + (size_t)64 * 1024 * 1024);
    short* c_bf  = (short*)(ws + (size_t)72 * 1024 * 1024);
    // xs_bf16 in front 64 MiB of d_out (dead before final GEMM writes it);
    // chunk carries (1 MiB) at d_out+100 MiB (also dead until final GEMM write).
    short* xs_bf = (short*)d_out;
    float* blkl  = (float*)((char*)d_out + (size_t)100 * 1024 * 1024);

    cast_kernel<<<SEQ * DIM / 4 / 256, 256, 0, stream>>>(xs, xs_bf, SEQ * DIM / 4);
    cast_kernel<<<DIM * DIM / 4 / 256, 256, 0, stream>>>(w_in, w_bf, DIM * DIM / 4);
    cast_kernel<<<DIM * DIM / 4 / 256, 256, 0, stream>>>(c_out, c_bf, DIM * DIM / 4);

    dim3 ggrid(DIM / 256, SEQ / 256);   // (8, 64): x==8 matches XCD round-robin
    gemm_bt<0><<<ggrid, 512, 0, stream>>>(xs_bf, w_bf, bxh, nullptr, nullptr, nullptr);

    dim3 sgrid(DIM / 512, NCHUNK);      // (4, 128)
    scan_pass1<<<sgrid, 256, 0, stream>>>(bxh, lam, blkl);
    scan_pass2<<<DIM / 512, 256, 0, stream>>>(blkl, lam);
    scan_pass3<<<sgrid, 256, 0, stream>>>(bxh, lam, blkl);

    gemm_bt<1><<<ggrid, 512, 0, stream>>>(bxh, c_bf, nullptr, out, xs, dskip);
}

// Round 2
// 567.585 us; speedup vs baseline: 1.1084x; 1.0064x over previous
//
#include <hip/hip_runtime.h>

#define SEQ   16384
#define DIM   2048
#define CHUNK 128
#define NCHUNK (SEQ / CHUNK)   // 128

typedef __attribute__((ext_vector_type(8))) short  short8;
typedef __attribute__((ext_vector_type(4))) short  short4v;
typedef __attribute__((ext_vector_type(4))) float  floatx4;

static __device__ __forceinline__ float bf2f(short s) {
    return __uint_as_float(((unsigned)(unsigned short)s) << 16);
}
static __device__ __forceinline__ short f2bf(float f) {
    unsigned u = __float_as_uint(f);
    u += 0x7fff + ((u >> 16) & 1);   // RNE
    return (short)(u >> 16);
}

// ---------- fp32 -> bf16 cast, float4 vectorized ----------
__global__ void cast_kernel(const float* __restrict__ in, short* __restrict__ out, int n4) {
    int i = blockIdx.x * blockDim.x + threadIdx.x;
    if (i >= n4) return;
    float4 v = ((const float4*)in)[i];
    short4v s;
    s.x = f2bf(v.x); s.y = f2bf(v.y); s.z = f2bf(v.z); s.w = f2bf(v.w);
    ((short4v*)out)[i] = s;
}

// ---------- bf16 GEMM, C[m][n] = sum_k A[m][k]*B[n][k] (both K-contiguous) ----------
// 256x256 tile, BK=64, 512 threads = 8 waves (2M x 4N), wave => 128x64 output.
// 8 single-barrier phases: [ds_reads; stage; MFMA; (vmcnt(6) at P4/P8); s_barrier].
// NO explicit lgkmcnt: compiler emits counted lgkm waits, interleaving ds_read
// service under the MFMA burst (within-phase overlap). Double-buffered 128 KiB
// LDS, XOR-8 slot swizzle (bank-conflict-free, verified 0 last round).
// FUSE==0: store bf16 C. FUSE==1: store fp32 C + xs*dskip.

#define BAR   __builtin_amdgcn_s_barrier()
#define PRIO1 __builtin_amdgcn_s_setprio(1)
#define PRIO0 __builtin_amdgcn_s_setprio(0)
#define VMC6  asm volatile("s_waitcnt vmcnt(6)" ::: "memory")
#define VMC0  asm volatile("s_waitcnt vmcnt(0)" ::: "memory")

// stage one 128x64 half-tile (16 KiB): 2 x global_load_lds(16B) per thread.
// LDS dest is linear (chunk c at shorts c*8); global source slot is XOR-swizzled
// so that a swizzled ds_read sees logical data (involution: s_src = s ^ (row&7)).
#define STAGE_A(b, h, t) do { \
    const short* _s = Abase + (size_t)(h) * 128 * K + (size_t)(t) * 64; \
    __builtin_amdgcn_global_load_lds(_s + gOff0, &As[b][h][c0 * 8], 16, 0, 0); \
    __builtin_amdgcn_global_load_lds(_s + gOff1, &As[b][h][c1 * 8], 16, 0, 0); \
} while (0)
#define STAGE_B(b, h, t) do { \
    const short* _s = Bbase + (size_t)(h) * 128 * K + (size_t)(t) * 64; \
    __builtin_amdgcn_global_load_lds(_s + gOff0, &Bs[b][h][c0 * 8], 16, 0, 0); \
    __builtin_amdgcn_global_load_lds(_s + gOff1, &Bs[b][h][c1 * 8], 16, 0, 0); \
} while (0)

// fragment reads: logical slot (ks*4+quad), physical slot XOR (row&7) = (l16&7)
#define LDA(b, mh) \
    _Pragma("unroll") \
    for (int mi = 0; mi < 4; mi++) { \
        _Pragma("unroll") \
        for (int ks = 0; ks < 2; ks++) \
            aV[mi][ks] = *(const short8*)&As[b][mh][(arow + mi * 16) * 64 + \
                                                    ((((ks << 2) | quad) ^ sx) << 3)]; \
    }
#define LDB(dst, b, nh) \
    _Pragma("unroll") \
    for (int ni = 0; ni < 2; ni++) { \
        _Pragma("unroll") \
        for (int ks = 0; ks < 2; ks++) \
            dst[ni][ks] = *(const short8*)&Bs[b][nh][(brow + ni * 16) * 64 + \
                                                     ((((ks << 2) | quad) ^ sx) << 3)]; \
    }
#define MMA(mh, nh, bR) \
    _Pragma("unroll") \
    for (int mi = 0; mi < 4; mi++) { \
        _Pragma("unroll") \
        for (int ni = 0; ni < 2; ni++) { \
            acc[mh][nh][mi][ni] = __builtin_amdgcn_mfma_f32_16x16x32_bf16( \
                aV[mi][0], bR[ni][0], acc[mh][nh][mi][ni], 0, 0, 0); \
            acc[mh][nh][mi][ni] = __builtin_amdgcn_mfma_f32_16x16x32_bf16( \
                aV[mi][1], bR[ni][1], acc[mh][nh][mi][ni], 0, 0, 0); \
        } \
    }

template<int FUSE>
__global__ __launch_bounds__(512, 2)
void gemm_bt(const short* __restrict__ A, const short* __restrict__ B,
             short* __restrict__ Cbf, float* __restrict__ Cf,
             const float* __restrict__ xs, const float* __restrict__ dskip)
{
    constexpr int K  = DIM;        // 2048
    constexpr int NT = K / 64;     // 32 K-tiles

    __shared__ alignas(16) short As[2][2][128 * 64];   // [buf][half][row*64+slot*8]
    __shared__ alignas(16) short Bs[2][2][128 * 64];

    const int tid = threadIdx.x;
    const int m0  = blockIdx.y * 256;
    const int n0  = blockIdx.x * 256;   // gridDim.x==8 == NXCD: one B-panel per XCD

    const int lane = tid & 63;
    const int wv   = tid >> 6;
    const int wrow = wv >> 2;           // 0..1
    const int wcol = wv & 3;            // 0..3
    const int l16  = lane & 15;
    const int quad = lane >> 4;
    const int sx   = l16 & 7;
    const int arow = wrow * 64 + l16;   // local row in A half-region (strided map)
    const int brow = wcol * 32 + l16;   // local row in B half-region

    // staging constants: chunks c0, c1 of each half-tile (1024 x 16B chunks)
    const int c0 = tid, c1 = tid + 512;
    const int r0 = c0 >> 3, r1 = c1 >> 3;
    const size_t gOff0 = (size_t)r0 * K + (size_t)((((c0 & 7) ^ (r0 & 7))) * 8);
    const size_t gOff1 = (size_t)r1 * K + (size_t)((((c1 & 7) ^ (r1 & 7))) * 8);
    const short* Abase = A + (size_t)m0 * K;
    const short* Bbase = B + (size_t)n0 * K;

    short8  aV[4][2], bA[2][2], bB[2][2];
    floatx4 acc[2][2][4][2] = {};   // [mh][nh][mi][ni]

    // ---- prologue: tile0 -> buf0 (8 loads), tile1 {Ah0,Bh0,Bh1} -> buf1 (6 loads)
    STAGE_A(0, 0, 0); STAGE_B(0, 0, 0); STAGE_B(0, 1, 0); STAGE_A(0, 1, 0);
    STAGE_A(1, 0, 1); STAGE_B(1, 0, 1); STAGE_B(1, 1, 1);
    VMC6;           // oldest 8 (= all of tile0) landed
    BAR;

    for (int i = 0; i < NT / 2; ++i) {
        const int t1 = 2 * i + 1;
        const int t2 = (2 * i + 2) & (NT - 1);   // wrap: tail stages harmless
        const int t3 = (2 * i + 3) & (NT - 1);

        // P1: read buf0.Ah0 + buf0.Bh0 ; stage buf1.Ah1 <- t1 ; MMA(0,0)
        LDA(0, 0); LDB(bA, 0, 0); STAGE_A(1, 1, t1);
        PRIO1; MMA(0, 0, bA); PRIO0;
        BAR;
        // P2: read buf0.Bh1 ; stage buf0.Ah0 <- t2 ; MMA(0,1)
        LDB(bB, 0, 1); STAGE_A(0, 0, t2);
        PRIO1; MMA(0, 1, bB); PRIO0;
        BAR;
        // P3: read buf0.Ah1 ; stage buf0.Bh0 <- t2 ; MMA(1,0)
        LDA(0, 1); STAGE_B(0, 0, t2);
        PRIO1; MMA(1, 0, bA); PRIO0;
        BAR;
        // P4: stage buf0.Bh1 <- t2 ; MMA(1,1) ; counted drain: buf1 fully ready
        STAGE_B(0, 1, t2);
        PRIO1; MMA(1, 1, bB); PRIO0;
        VMC6;
        BAR;
        // P5: read buf1.Ah0 + buf1.Bh0 ; stage buf0.Ah1 <- t2 ; MMA(0,0)
        LDA(1, 0); LDB(bA, 1, 0); STAGE_A(0, 1, t2);
        PRIO1; MMA(0, 0, bA); PRIO0;
        BAR;
        // P6: read buf1.Bh1 ; stage buf1.Ah0 <- t3 ; MMA(0,1)
        LDB(bB, 1, 1); STAGE_A(1, 0, t3);
        PRIO1; MMA(0, 1, bB); PRIO0;
        BAR;
        // P7: read buf1.Ah1 ; stage buf1.Bh0 <- t3 ; MMA(1,0)
        LDA(1, 1); STAGE_B(1, 0, t3);
        PRIO1; MMA(1, 0, bA); PRIO0;
        BAR;
        // P8: stage buf1.Bh1 <- t3 ; MMA(1,1) ; counted drain: buf0 fully ready
        STAGE_B(1, 1, t3);
        PRIO1; MMA(1, 1, bB); PRIO0;
        VMC6;
        BAR;
    }
    VMC0;   // no LDS-DMA may outlive this workgroup

    // ---- epilogue: C row = m0+wrow*64+mh*128+mi*16+quad*4+r, col = n0+wcol*32+nh*128+ni*16+l16
    if (FUSE == 0) {
        #pragma unroll
        for (int mh = 0; mh < 2; mh++)
        #pragma unroll
        for (int mi = 0; mi < 4; mi++) {
            const int rb = m0 + wrow * 64 + mh * 128 + mi * 16 + quad * 4;
            #pragma unroll
            for (int nh = 0; nh < 2; nh++)
            #pragma unroll
            for (int ni = 0; ni < 2; ni++) {
                const int cc = n0 + wcol * 32 + nh * 128 + ni * 16 + l16;
                #pragma unroll
                for (int r = 0; r < 4; r++)
                    Cbf[(size_t)(rb + r) * DIM + cc] = f2bf(acc[mh][nh][mi][ni][r]);
            }
        }
    } else {
        float dsk[2][2];
        #pragma unroll
        for (int nh = 0; nh < 2; nh++)
        #pragma unroll
        for (int ni = 0; ni < 2; ni++)
            dsk[nh][ni] = dskip[n0 + wcol * 32 + nh * 128 + ni * 16 + l16];
        #pragma unroll
        for (int mh = 0; mh < 2; mh++)
        #pragma unroll
        for (int mi = 0; mi < 4; mi++) {
            const int rb = m0 + wrow * 64 + mh * 128 + mi * 16 + quad * 4;
            #pragma unroll
            for (int nh = 0; nh < 2; nh++)
            #pragma unroll
            for (int ni = 0; ni < 2; ni++) {
                const int cc = n0 + wcol * 32 + nh * 128 + ni * 16 + l16;
                #pragma unroll
                for (int r = 0; r < 4; r++) {
                    size_t idx = (size_t)(rb + r) * DIM + cc;
                    Cf[idx] = acc[mh][nh][mi][ni][r] + xs[idx] * dsk[nh][ni];
                }
            }
        }
    }
}

// ---------- scan pass 1: per-chunk local final state (zero init), 4 cols/thread ----------
__global__ void scan_pass1(const short* __restrict__ bx, const float* __restrict__ lam,
                           float* __restrict__ blockLast)
{
    int q     = blockIdx.x * 256 + threadIdx.x;   // 4-col group id, q < DIM/4
    int n     = q * 4;
    int chunk = blockIdx.y;
    float4 lm = *(const float4*)&lam[n];
    const uint2* p = (const uint2*)(bx + (size_t)chunk * CHUNK * DIM) + q;
    float h0 = 0.f, h1 = 0.f, h2 = 0.f, h3 = 0.f;
    #pragma unroll 16
    for (int i = 0; i < CHUNK; i++) {
        uint2 v = p[(size_t)i * (DIM / 4)];
        h0 = fmaf(lm.x, h0, bf2f((short)(v.x & 0xffffu)));
        h1 = fmaf(lm.y, h1, bf2f((short)(v.x >> 16)));
        h2 = fmaf(lm.z, h2, bf2f((short)(v.y & 0xffffu)));
        h3 = fmaf(lm.w, h3, bf2f((short)(v.y >> 16)));
    }
    float4 o; o.x = h0; o.y = h1; o.z = h2; o.w = h3;
    *(float4*)&blockLast[(size_t)chunk * DIM + n] = o;
}

// ---------- scan pass 2: exclusive prefix over chunks (in place), 4 cols/thread ----------
__global__ void scan_pass2(float* __restrict__ blockLast, const float* __restrict__ lam)
{
    int q = blockIdx.x * 256 + threadIdx.x;
    int n = q * 4;
    float4 lm = *(const float4*)&lam[n];
    float p0 = lm.x, p1 = lm.y, p2 = lm.z, p3 = lm.w;
    #pragma unroll
    for (int i = 0; i < 7; i++) { p0 *= p0; p1 *= p1; p2 *= p2; p3 *= p3; }  // lam^128
    float c0 = 0.f, c1 = 0.f, c2 = 0.f, c3 = 0.f;
    for (int c = 0; c < NCHUNK; c++) {
        float4* qp = (float4*)&blockLast[(size_t)c * DIM + n];
        float4 t = *qp;
        float4 w; w.x = c0; w.y = c1; w.z = c2; w.w = c3;
        *qp = w;
        c0 = fmaf(p0, c0, t.x);
        c1 = fmaf(p1, c1, t.y);
        c2 = fmaf(p2, c2, t.z);
        c3 = fmaf(p3, c3, t.w);
    }
}

// ---------- scan pass 3: apply carry, write hs (bf16, in place over bx), 4 cols/thread ----------
__global__ void scan_pass3(short* __restrict__ bxh, const float* __restrict__ lam,
                           const float* __restrict__ carry)
{
    int q     = blockIdx.x * 256 + threadIdx.x;
    int n     = q * 4;
    int chunk = blockIdx.y;
    float4 lm = *(const float4*)&lam[n];
    float4 cv = *(const float4*)&carry[(size_t)chunk * DIM + n];
    float h0 = cv.x, h1 = cv.y, h2 = cv.z, h3 = cv.w;
    uint2* p = (uint2*)(bxh + (size_t)chunk * CHUNK * DIM) + q;
    #pragma unroll 16
    for (int i = 0; i < CHUNK; i++) {
        uint2 v = p[(size_t)i * (DIM / 4)];
        h0 = fmaf(lm.x, h0, bf2f((short)(v.x & 0xffffu)));
        h1 = fmaf(lm.y, h1, bf2f((short)(v.x >> 16)));
        h2 = fmaf(lm.z, h2, bf2f((short)(v.y & 0xffffu)));
        h3 = fmaf(lm.w, h3, bf2f((short)(v.y >> 16)));
        uint2 o;
        o.x = (unsigned)(unsigned short)f2bf(h0) | ((unsigned)(unsigned short)f2bf(h1) << 16);
        o.y = (unsigned)(unsigned short)f2bf(h2) | ((unsigned)(unsigned short)f2bf(h3) << 16);
        p[(size_t)i * (DIM / 4)] = o;
    }
}

extern "C" void kernel_launch(void* const* d_in, const int* in_sizes, int n_in,
                              void* d_out, int out_size, void* d_ws, size_t ws_size,
                              hipStream_t stream)
{
    const float* xs    = (const float*)d_in[0];
    const float* lam   = (const float*)d_in[1];
    const float* w_in  = (const float*)d_in[2];
    const float* c_out = (const float*)d_in[3];
    const float* dskip = (const float*)d_in[4];
    float* out = (float*)d_out;

    // ws layout:
    //   [0,   64M) : bx / hs  bf16  [SEQ][DIM]
    //   [64M, 72M) : w_in     bf16  [DIM][DIM]
    //   [72M, 80M) : c_out    bf16  [DIM][DIM]
    char*  ws    = (char*)d_ws;
    short* bxh   = (short*)ws;
    short* w_bf  = (short*)(ws + (size_t)64 * 1024 * 1024);
    short* c_bf  = (short*)(ws + (size_t)72 * 1024 * 1024);
    // xs_bf16 in front 64 MiB of d_out (dead before final GEMM writes it);
    // chunk carries (1 MiB) at d_out+100 MiB (also dead until final GEMM write).
    short* xs_bf = (short*)d_out;
    float* blkl  = (float*)((char*)d_out + (size_t)100 * 1024 * 1024);

    cast_kernel<<<SEQ * DIM / 4 / 256, 256, 0, stream>>>(xs, xs_bf, SEQ * DIM / 4);
    cast_kernel<<<DIM * DIM / 4 / 256, 256, 0, stream>>>(w_in, w_bf, DIM * DIM / 4);
    cast_kernel<<<DIM * DIM / 4 / 256, 256, 0, stream>>>(c_out, c_bf, DIM * DIM / 4);

    dim3 ggrid(DIM / 256, SEQ / 256);   // (8, 64): x==8 matches XCD round-robin
    gemm_bt<0><<<ggrid, 512, 0, stream>>>(xs_bf, w_bf, bxh, nullptr, nullptr, nullptr);

    dim3 sgrid(DIM / 1024, NCHUNK);     // (2, 128)
    scan_pass1<<<sgrid, 256, 0, stream>>>(bxh, lam, blkl);
    scan_pass2<<<DIM / 1024, 256, 0, stream>>>(blkl, lam);
    scan_pass3<<<sgrid, 256, 0, stream>>>(bxh, lam, blkl);

    gemm_bt<1><<<ggrid, 512, 0, stream>>>(bxh, c_bf, nullptr, out, xs, dskip);
}